// Round 9
// baseline (167.947 us; speedup 1.0000x reference)
//
#include <hip/hip_runtime.h>

namespace {
constexpr int T_ = 1024;
constexpr int NBATCH = 256;

// ---- d_ws layout (bytes) ----
constexpr int WFB_OFF    = 0;         // 144 x 288 bf16 (stage1+A1, dh1-major K)
constexpr int WFC_OFF    = 82944;     // 48 x 1440 bf16 (stage2+A2, dh-major K)
constexpr int WFD_OFF    = 221184;    // 16 x 320 bf16 (conv1d5*bn1, d-major K)
constexpr int WBIG_OFF   = 231424;    // 16 x 672 bf16 (FULL composite, dt-major)
constexpr int WFE_OFF    = 252928;    // 16 x 64 bf16 (conv1d3*bn2, d-major)
constexpr int BIASB_OFF  = 254976;    // 144 f32
constexpr int BIASC_OFF  = 255552;    // 48 f32
constexpr int BIASD_OFF  = 255744;    // 16 f32
constexpr int BIASBIG_OFF= 255808;    // 16 f32
constexpr int BIASE_OFF  = 255872;    // 8 f32

// prep flat-section ranges
constexpr int S0 = 41472;             // wfB
constexpr int S1 = S0 + 69120;        // wfC
constexpr int S2 = S1 + 5120;         // wfD
constexpr int S3 = S2 + 1024;         // wfE
constexpr int S4 = S3 + 144;          // biasB
constexpr int S5 = S4 + 48;           // biasC
constexpr int S6 = S5 + 16;           // biasD
constexpr int S7 = S6 + 8;            // biasE
constexpr int NPREP = 115;            // flat blocks; + 16 wBIG blocks

// ---- fused kernel LDS (bytes): max(main 27392, fixup 38592) ----
constexpr int SLAB_OFF  = 0;                     // main: 292 rows x 64 B
constexpr int H1_OFF    = 18688;                 // main: 272 rows x 32 B -> 27392
constexpr int TT_FX     = 50;
constexpr int FXF2IN    = 0;                     // 72 rows x 320
constexpr int FXF3      = FXF2IN + 72 * 320;     // 23040: 68 rows x 144
constexpr int FXSLAB    = FXF3 + 68 * 144;       // 32832: 72 rows x 80
constexpr int FXH1      = FXSLAB;                // overlay: 52 rows x 68B
constexpr int SMEM_FUSE = FXSLAB + 72 * 80;      // 38592
static_assert(SMEM_FUSE <= 65536, "fused LDS");

typedef __attribute__((ext_vector_type(8))) short short8v;
typedef __attribute__((ext_vector_type(4))) float f32x4;

__device__ inline unsigned short f2b(float f) {
  union { float f; unsigned u; } v; v.f = f;
  unsigned r = (v.u + 0x7FFFu + ((v.u >> 16) & 1u)) >> 16;
  return (unsigned short)r;
}
__device__ inline float b2f(unsigned short u) {
  union { unsigned u; float f; } v; v.u = ((unsigned)u) << 16;
  return v.f;
}
__device__ inline int fx_f2in_byte(int row, int slot, int within) {
  return FXF2IN + row * 320 + ((slot ^ ((row >> 2) & 3)) << 4) + within;
}
}

// ============ prep: ALL tables in one launch ================================
// blocks [0,NPREP): flat fill of wfB/wfC/wfD/wfE/biasB..E.
// blocks [NPREP, NPREP+16): per-o3 wBIG + biasBIG via LDS-local wComp fold.
__global__ __launch_bounds__(256) void prep_kernel(
    const float* __restrict__ A1, const float* __restrict__ A2,
    const float* __restrict__ W1, const float* __restrict__ b1,
    const float* __restrict__ W2, const float* __restrict__ b2,
    const float* __restrict__ Wc1, const float* __restrict__ bc1,
    const float* __restrict__ bn1w, const float* __restrict__ bn1b,
    const float* __restrict__ bn1m, const float* __restrict__ bn1v,
    const float* __restrict__ Wc2, const float* __restrict__ bc2,
    const float* __restrict__ bn2w, const float* __restrict__ bn2b,
    const float* __restrict__ bn2m, const float* __restrict__ bn2v,
    unsigned char* __restrict__ ws) {
  __shared__ float wcl[13 * 144];     // wComp[o3] local (7488 B)
  __shared__ float slice[48 * 144];   // wfC dh-slice / wfB dh1-slice (27648 B)
  __shared__ float pb[192];
  const int tid = threadIdx.x;

  if (blockIdx.x < NPREP) {
    unsigned short* wfB = (unsigned short*)(ws + WFB_OFF);
    unsigned short* wfC = (unsigned short*)(ws + WFC_OFF);
    unsigned short* wfD = (unsigned short*)(ws + WFD_OFF);
    unsigned short* wfE = (unsigned short*)(ws + WFE_OFF);
    float* biasB = (float*)(ws + BIASB_OFF);
    float* biasC = (float*)(ws + BIASC_OFF);
    float* biasD = (float*)(ws + BIASD_OFF);
    float* biasE = (float*)(ws + BIASE_OFF);
    for (int idx = blockIdx.x * 256 + tid; idx < S7; idx += NPREP * 256) {
      if (idx < S0) {                      // wfB[ncol][dh1*32+m1]
        int ncol = idx / 288, k = idx - ncol * 288;
        int dh = k >> 5, mm = k & 31;
        float val = 0.f;
        if (mm < 27) {
          int v = mm / 3, ci = mm - v * 3;
          int p = ncol / 48, rr = ncol - p * 48, c = rr / 3, e = rr - c * 3;
          int w = p * 3 + e;
          for (int k5 = 0; k5 < 5; ++k5)
            val += W1[(k5 * 16 + c) * 27 + ci * 9 + dh] * A1[k5 * 81 + v * 9 + w];
        }
        wfB[idx] = f2b(val);
      } else if (idx < S1) {               // wfC[nc][dh*160+off]
        int i2 = idx - S0;
        int nc = i2 / 1440, k = i2 - nc * 1440;
        int dh = k / 160, off = k - dh * 160;
        float val = 0.f;
        if (off < 144) {
          int p = off / 48, ci2 = off - p * 48;
          int c2 = nc / 3, w2 = nc - c2 * 3;
          for (int k2 = 0; k2 < 3; ++k2)
            val += W2[(k2 * 16 + c2) * 432 + ci2 * 9 + dh] * A2[k2 * 9 + p * 3 + w2];
        }
        wfC[i2] = f2b(val);
      } else if (idx < S2) {               // wfD[o3][d*64+nc]
        int i3 = idx - S1;
        int o3 = i3 / 320, k = i3 - o3 * 320;
        int d = k >> 6, nc = k & 63;
        float val = 0.f;
        if (nc < 48) {
          float s1 = bn1w[o3] * rsqrtf(bn1v[o3] + 1e-5f);
          val = Wc1[o3 * 240 + nc * 5 + d] * s1;
        }
        wfD[i3] = f2b(val);
      } else if (idx < S3) {               // wfE[o4p][d*16+ci]*s2
        int i4 = idx - S2;
        int o4 = i4 >> 6, k = i4 & 63;
        float val = 0.f;
        if (o4 < 8 && k < 48) {
          int d = k >> 4, ci = k & 15;
          float s2 = bn2w[o4] * rsqrtf(bn2v[o4] + 1e-5f);
          val = Wc2[(o4 * 16 + ci) * 3 + d] * s2;
        }
        wfE[i4] = f2b(val);
      } else if (idx < S4) {               // biasB
        int ib = idx - S3;
        int p = ib / 48, rr = ib - p * 48, c = rr / 3, e = rr - c * 3;
        int w = p * 3 + e;
        float val = 0.f;
        for (int k5 = 0; k5 < 5; ++k5)
          for (int v = 0; v < 9; ++v)
            val += b1[k5 * 16 + c] * A1[k5 * 81 + v * 9 + w];
        biasB[ib] = val;
      } else if (idx < S5) {               // biasC
        int nc = idx - S4, c2 = nc / 3, w2 = nc - c2 * 3;
        float val = 0.f;
        for (int k2 = 0; k2 < 3; ++k2)
          for (int p = 0; p < 3; ++p)
            val += b2[k2 * 16 + c2] * A2[k2 * 9 + p * 3 + w2];
        biasC[nc] = val;
      } else if (idx < S6) {               // biasD
        int o3 = idx - S5;
        float s1 = bn1w[o3] * rsqrtf(bn1v[o3] + 1e-5f);
        biasD[o3] = bc1[o3] * s1 + bn1b[o3] - bn1m[o3] * s1;
      } else {                             // biasE
        int o4 = idx - S6;
        float s2 = bn2w[o4] * rsqrtf(bn2v[o4] + 1e-5f);
        biasE[o4] = bc2[o4] * s2 + bn2b[o4] - bn2m[o4] * s2;
      }
    }
    return;
  }

  // ---- wBIG block for o3 ----
  const int o3 = blockIdx.x - NPREP;
  const float s1 = bn1w[o3] * rsqrtf(bn1v[o3] + 1e-5f);
  unsigned short* wBIG = (unsigned short*)(ws + WBIG_OFF);

  for (int i = tid; i < 1872; i += 256) wcl[i] = 0.f;
  __syncthreads();
  // wComp[dh2][ncol] = sum_d sum_nc Wc1s[nc][d] * wfC32[nc][dh2-d][ncol]
  for (int dh = 0; dh < 9; ++dh) {
    for (int i = tid; i < 6912; i += 256) {
      int nc = i / 144, ncol = i - nc * 144;
      int p = ncol / 48, ci2 = ncol - p * 48;
      int c2 = nc / 3, w2 = nc - c2 * 3;
      float v = 0.f;
      for (int k2 = 0; k2 < 3; ++k2)
        v += W2[(k2 * 16 + c2) * 432 + ci2 * 9 + dh] * A2[k2 * 9 + p * 3 + w2];
      slice[i] = v;
    }
    __syncthreads();
    if (tid < 144) {
#pragma unroll
      for (int d = 0; d < 5; ++d) {
        float wv = 0.f;
        for (int nc = 0; nc < 48; ++nc)
          wv += Wc1[o3 * 240 + nc * 5 + d] * slice[nc * 144 + tid];
        wcl[(dh + d) * 144 + tid] += wv * s1;
      }
    }
    __syncthreads();
  }

  // fold: wBIG[dt][mm] = sum_dh1 sum_ncol wfB[ncol][dh1][mm] * wComp[dt-dh1][ncol]
  float acc0 = 0.f, acc1 = 0.f, acc2 = 0.f;
  const int sl0 = tid, sl1 = tid + 256, sl2 = tid + 512;
  for (int dh1 = 0; dh1 < 9; ++dh1) {
    for (int i = tid; i < 3888; i += 256) {       // wfBs[ncol][m]
      int ncol = i / 27, m = i - ncol * 27;
      int vv = m / 3, ci = m - vv * 3;
      int p = ncol / 48, rr = ncol - p * 48, c = rr / 3, e = rr - c * 3;
      int w = p * 3 + e;
      float val = 0.f;
      for (int k5 = 0; k5 < 5; ++k5)
        val += W1[(k5 * 16 + c) * 27 + ci * 9 + dh1] * A1[k5 * 81 + vv * 9 + w];
      slice[i] = val;
    }
    __syncthreads();
    {
      int dt = sl0 >> 5, mm = sl0 & 31, dh2 = dt - dh1;
      if (mm < 27 && dh2 >= 0 && dh2 <= 12)
        for (int ncol = 0; ncol < 144; ++ncol)
          acc0 += wcl[dh2 * 144 + ncol] * slice[ncol * 27 + mm];
    }
    {
      int dt = sl1 >> 5, mm = sl1 & 31, dh2 = dt - dh1;
      if (mm < 27 && dh2 >= 0 && dh2 <= 12)
        for (int ncol = 0; ncol < 144; ++ncol)
          acc1 += wcl[dh2 * 144 + ncol] * slice[ncol * 27 + mm];
    }
    if (sl2 < 672) {
      int dt = sl2 >> 5, mm = sl2 & 31, dh2 = dt - dh1;
      if (mm < 27 && dh2 >= 0 && dh2 <= 12)
        for (int ncol = 0; ncol < 144; ++ncol)
          acc2 += wcl[dh2 * 144 + ncol] * slice[ncol * 27 + mm];
    }
    __syncthreads();
  }
  wBIG[o3 * 672 + sl0] = f2b(((sl0 & 31) < 27) ? acc0 : 0.f);
  wBIG[o3 * 672 + sl1] = f2b(((sl1 & 31) < 27) ? acc1 : 0.f);
  if (sl2 < 672) wBIG[o3 * 672 + sl2] = f2b(((sl2 & 31) < 27) ? acc2 : 0.f);

  // biasBIG (self-contained: local biasB/biasC)
  if (tid < 144) {
    int p = tid / 48, rr = tid - p * 48, c = rr / 3, e = rr - c * 3;
    int w = p * 3 + e;
    float val = 0.f;
    for (int k5 = 0; k5 < 5; ++k5)
      for (int v = 0; v < 9; ++v)
        val += b1[k5 * 16 + c] * A1[k5 * 81 + v * 9 + w];
    pb[tid] = val;
  } else if (tid < 192) {
    int nc = tid - 144, c2 = nc / 3, w2 = nc - c2 * 3;
    float val = 0.f;
    for (int k2 = 0; k2 < 3; ++k2)
      for (int p = 0; p < 3; ++p)
        val += b2[k2 * 16 + c2] * A2[k2 * 9 + p * 3 + w2];
    pb[tid] = val;
  }
  __syncthreads();
  if (tid < 144) {
    float s = 0.f;
    for (int dh2 = 0; dh2 < 13; ++dh2) s += wcl[dh2 * 144 + tid];
    slice[tid] = s * pb[tid];
  } else if (tid < 192) {
    int nc = tid - 144;
    float s = 0.f;
#pragma unroll
    for (int d = 0; d < 5; ++d) s += Wc1[o3 * 240 + nc * 5 + d];
    slice[tid] = s * s1 * pb[tid];
  }
  __syncthreads();
  if (tid == 0) {
    float accb = bc1[o3] * s1 + bn1b[o3] - bn1m[o3] * s1;
    for (int i = 0; i < 192; ++i) accb += slice[i];
    ((float*)(ws + BIASBIG_OFF))[o3] = accb;
  }
}

// ============ fused: main composite (bx<4) + boundary fixup (bx 4,5) ========
__global__ __launch_bounds__(256, 3) void fused_kernel(
    const float* __restrict__ poses,
    const float* __restrict__ Wc2, const float* __restrict__ bc2,
    const float* __restrict__ bn2w, const float* __restrict__ bn2b,
    const float* __restrict__ bn2m, const float* __restrict__ bn2v,
    const unsigned char* __restrict__ ws, float* __restrict__ out) {
  __shared__ __attribute__((aligned(16))) unsigned char smem[SMEM_FUSE];
  const int tid = threadIdx.x;
  const int n = blockIdx.y;
  const int w = tid >> 6, l = tid & 63, lrow = l & 15, q = l >> 4, q8 = q * 8;

  if (blockIdx.x < 4) {
    // ================= MAIN path =================
    const int t0 = blockIdx.x * 256;
    {
      unsigned* s32 = (unsigned*)(smem + SLAB_OFF);
      for (int idx = tid; idx < 292 * 16; idx += 256) {
        int r = idx >> 4, mi = idx & 15, m0 = mi * 2;
        int t = t0 - 18 + r;
        float v0 = 0.f, v1 = 0.f;
        if (t >= 0 && t < T_) {
          const float* src = poses + ((long)n * T_ + t) * 27;
          if (m0 < 27) v0 = src[m0];
          if (m0 + 1 < 27) v1 = src[m0 + 1];
        }
        s32[idx] = (unsigned)f2b(v0) | ((unsigned)f2b(v1) << 16);
      }
    }

    const float bb = ((const float*)(ws + BIASBIG_OFF))[lrow];
    const float be = ((const float*)(ws + BIASE_OFF))[lrow & 7];
    // B-frags direct from global (L2-resident table)
    const unsigned short* wbg = (const unsigned short*)(ws + WBIG_OFF);
    short8v B[21];
#pragma unroll
    for (int dt = 0; dt < 21; ++dt)
      B[dt] = *(const short8v*)(wbg + lrow * 672 + dt * 32 + q8);
    const unsigned short* wfe = (const unsigned short*)(ws + WFE_OFF);
    const short8v E0 = *(const short8v*)(wfe + lrow * 64 + q8);
    const short8v E1 = *(const short8v*)(wfe + lrow * 64 + 32 + q8);
    __syncthreads();

    // BIG GEMM: 272 h1 rows (t = t0-8+lr), 17 mt over waves
#pragma unroll
    for (int i = 0; i < 5; ++i) {
      if (i == 4 && w != 0) continue;
      const int mt = (i < 4) ? (w + i * 4) : 16;
      const int sbase = SLAB_OFF + (mt * 16 + lrow) * 64 + q8 * 2;
      f32x4 c0 = {0.f, 0.f, 0.f, 0.f}, c1 = {0.f, 0.f, 0.f, 0.f};
      short8v a[7];
#pragma unroll
      for (int dt = 0; dt < 7; ++dt) a[dt] = *(const short8v*)(smem + sbase + dt * 64);
#pragma unroll
      for (int dt = 0; dt < 7; ++dt) {
        if (dt & 1) c1 = __builtin_amdgcn_mfma_f32_16x16x32_bf16(a[dt], B[dt], c1, 0, 0, 0);
        else        c0 = __builtin_amdgcn_mfma_f32_16x16x32_bf16(a[dt], B[dt], c0, 0, 0, 0);
      }
#pragma unroll
      for (int dt = 0; dt < 7; ++dt) a[dt] = *(const short8v*)(smem + sbase + (7 + dt) * 64);
#pragma unroll
      for (int dt = 0; dt < 7; ++dt) {
        if (dt & 1) c1 = __builtin_amdgcn_mfma_f32_16x16x32_bf16(a[dt], B[7 + dt], c1, 0, 0, 0);
        else        c0 = __builtin_amdgcn_mfma_f32_16x16x32_bf16(a[dt], B[7 + dt], c0, 0, 0, 0);
      }
#pragma unroll
      for (int dt = 0; dt < 7; ++dt) a[dt] = *(const short8v*)(smem + sbase + (14 + dt) * 64);
#pragma unroll
      for (int dt = 0; dt < 7; ++dt) {
        if (dt & 1) c1 = __builtin_amdgcn_mfma_f32_16x16x32_bf16(a[dt], B[14 + dt], c1, 0, 0, 0);
        else        c0 = __builtin_amdgcn_mfma_f32_16x16x32_bf16(a[dt], B[14 + dt], c0, 0, 0, 0);
      }
      const int hbase = H1_OFF + (mt * 16 + q * 4) * 32 + lrow * 2;
#pragma unroll
      for (int jj = 0; jj < 4; ++jj) {
        float x = c0[jj] + c1[jj] + bb;
        float h = x > 0.f ? x : 0.01f * x;
        *(unsigned short*)(smem + hbase + jj * 32) = f2b(h);
      }
    }
    __syncthreads();

    // E GEMM; skip boundary rows (written by fixup blocks)
#pragma unroll
    for (int i = 0; i < 4; ++i) {
      const int mte = w + i * 4;
      const int abase = H1_OFF + (7 + mte * 16 + lrow) * 32 + q8 * 2;
      short8v A0v = *(const short8v*)(smem + abase);
      short8v A1v = *(const short8v*)(smem + abase + 64);
      f32x4 acc = {0.f, 0.f, 0.f, 0.f};
      acc = __builtin_amdgcn_mfma_f32_16x16x32_bf16(A0v, E0, acc, 0, 0, 0);
      acc = __builtin_amdgcn_mfma_f32_16x16x32_bf16(A1v, E1, acc, 0, 0, 0);
      if (lrow < 8) {
        const int tb = t0 + mte * 16 + q * 4;
#pragma unroll
        for (int jj = 0; jj < 4; ++jj) {
          const int t = tb + jj;
          if (t >= 7 && t < 1017) {
            float x = acc[jj] + be;
            out[((long)n * T_ + t) * 8 + lrow] = x > 0.f ? x : 0.01f * x;
          }
        }
      }
    }
    return;
  }

  // ================= FIXUP path (boundary rows only) =================
  const unsigned short* wfB = (const unsigned short*)(ws + WFB_OFF);
  const unsigned short* wfC = (const unsigned short*)(ws + WFC_OFF);
  const unsigned short* wfD = (const unsigned short*)(ws + WFD_OFF);
  const float* biasB = (const float*)(ws + BIASB_OFF);
  const float* biasC = (const float*)(ws + BIASC_OFF);
  const float* biasD = (const float*)(ws + BIASD_OFF);
  const int e = blockIdx.x - 4;
  const int t0 = e ? (T_ - TT_FX) : 0;

  {
    unsigned* slab32 = (unsigned*)(smem + FXSLAB);
    for (int it = tid; it < 72 * 20; it += 256) {
      int r = it / 20, mi = it - r * 20;
      int t = t0 - 11 + r;
      int m0 = mi * 2;
      float v0 = 0.f, v1 = 0.f;
      if (t >= 0 && t < T_) {
        const float* src = poses + ((long)n * T_ + t) * 27;
        if (m0 < 27) v0 = src[m0];
        if (m0 + 1 < 27) v1 = src[m0 + 1];
      }
      slab32[it] = (unsigned)f2b(v0) | ((unsigned)f2b(v1) << 16);
    }
    for (int it = tid; it < 64 * 8; it += 256) {
      int r = it >> 3, u = it & 7;
      int s = 18 + (u >> 2);
      *(unsigned*)(smem + fx_f2in_byte(r, s, (u & 3) * 4)) = 0;
    }
    for (int it = tid; it < 8 * 80; it += 256) {
      int r = 64 + it / 80, u = it - (it / 80) * 80;
      *(unsigned*)(smem + FXF2IN + r * 320 + u * 4) = 0;
    }
    for (int it = tid; it < 68 * 8 + 12 * 24; it += 256) {
      if (it < 68 * 8) {
        int r = it >> 3, u = it & 7;
        *(unsigned*)(smem + FXF3 + r * 144 + 96 + u * 4) = 0;
      } else {
        int k2 = it - 68 * 8;
        int r = 56 + k2 / 24, u = k2 - (k2 / 24) * 24;
        *(unsigned*)(smem + FXF3 + r * 144 + u * 4) = 0;
      }
    }
  }
  __syncthreads();

  {  // GEMM B
    const int ntS = (w == 0) ? 0 : (2 * w + 1);
    const int ntN = (w == 0) ? 3 : 2;
#pragma unroll
    for (int ni = 0; ni < 3; ++ni) {
      if (ni < ntN) {
        const int nt = ntS + ni;
        short8v b[9];
#pragma unroll
        for (int dh = 0; dh < 9; ++dh)
          b[dh] = *(const short8v*)(wfB + (nt * 16 + lrow) * 288 + dh * 32 + q8);
        const int ncol = nt * 16 + lrow;
        const float bias = biasB[ncol];
#pragma unroll
        for (int mt = 0; mt < 4; ++mt) {
          short8v a[9];
#pragma unroll
          for (int dh = 0; dh < 9; ++dh)
            a[dh] = *(const short8v*)(smem + FXSLAB + ((mt * 16 + lrow + dh) * 40 + q8) * 2);
          f32x4 c0 = {0.f, 0.f, 0.f, 0.f}, c1 = {0.f, 0.f, 0.f, 0.f};
#pragma unroll
          for (int dh = 0; dh < 9; ++dh) {
            if (dh & 1) c1 = __builtin_amdgcn_mfma_f32_16x16x32_bf16(a[dh], b[dh], c1, 0, 0, 0);
            else        c0 = __builtin_amdgcn_mfma_f32_16x16x32_bf16(a[dh], b[dh], c0, 0, 0, 0);
          }
#pragma unroll
          for (int jj = 0; jj < 4; ++jj) {
            const int r = mt * 16 + q * 4 + jj;
            const int t = t0 - 7 + r;
            float v = (t >= 0 && t < T_) ? c0[jj] + c1[jj] + bias : 0.f;
            *(unsigned short*)(smem + fx_f2in_byte(r, ncol >> 3, (ncol & 7) * 2)) = f2b(v);
          }
        }
      }
    }
  }
  __syncthreads();

  if (w < 3) {  // GEMM C
    const int ncol2 = w * 16 + lrow;
    const float bias = biasC[ncol2];
    f32x4 acc[4];
#pragma unroll
    for (int mt = 0; mt < 4; ++mt) acc[mt] = {0.f, 0.f, 0.f, 0.f};
#pragma unroll
    for (int g = 0; g < 5; ++g) {
      short8v b[9];
#pragma unroll
      for (int i = 0; i < 9; ++i) {
        const int kf = g * 9 + i, dh = kf / 5, kkl = kf % 5;
        b[i] = *(const short8v*)(wfC + ncol2 * 1440 + dh * 160 + kkl * 32 + q8);
      }
#pragma unroll
      for (int mt = 0; mt < 4; ++mt) {
        short8v a[9];
#pragma unroll
        for (int i = 0; i < 9; ++i) {
          const int kf = g * 9 + i, dh = kf / 5, kkl = kf % 5;
          a[i] = *(const short8v*)(smem + fx_f2in_byte(mt * 16 + lrow + dh, 4 * kkl + q, 0));
        }
#pragma unroll
        for (int i = 0; i < 9; ++i)
          acc[mt] = __builtin_amdgcn_mfma_f32_16x16x32_bf16(a[i], b[i], acc[mt], 0, 0, 0);
      }
    }
#pragma unroll
    for (int mt = 0; mt < 4; ++mt) {
#pragma unroll
      for (int jj = 0; jj < 4; ++jj) {
        const int rt3 = mt * 16 + q * 4 + jj;
        if (rt3 < 56) {
          const int t = t0 - 3 + rt3;
          float v = (t >= 0 && t < T_) ? acc[mt][jj] + bias : 0.f;
          *(unsigned short*)(smem + FXF3 + rt3 * 144 + ncol2 * 2) = f2b(v);
        }
      }
    }
  }
  __syncthreads();

  {  // GEMM D
    const int arow = w * 16 + lrow;
    short8v a[10], b[10];
#pragma unroll
    for (int kf = 0; kf < 10; ++kf) {
      const int d = kf >> 1, kkl = kf & 1;
      b[kf] = *(const short8v*)(wfD + lrow * 320 + d * 64 + kkl * 32 + q8);
      a[kf] = *(const short8v*)(smem + FXF3 + (arow + d) * 144 + (kkl * 32 + q8) * 2);
    }
    f32x4 c0 = {0.f, 0.f, 0.f, 0.f}, c1 = {0.f, 0.f, 0.f, 0.f};
#pragma unroll
    for (int kf = 0; kf < 10; ++kf) {
      if (kf & 1) c1 = __builtin_amdgcn_mfma_f32_16x16x32_bf16(a[kf], b[kf], c1, 0, 0, 0);
      else        c0 = __builtin_amdgcn_mfma_f32_16x16x32_bf16(a[kf], b[kf], c0, 0, 0, 0);
    }
    const float bias = biasD[lrow];
#pragma unroll
    for (int jj = 0; jj < 4; ++jj) {
      const int rh = w * 16 + q * 4 + jj;
      if (rh < 52) {
        const int t = t0 - 1 + rh;
        float v = 0.f;
        if (t >= 0 && t < T_) {
          float x = c0[jj] + c1[jj] + bias;
          v = x > 0.f ? x : 0.01f * x;
        }
        *(float*)(smem + FXH1 + (rh * 17 + lrow) * 4) = v;
      }
    }
  }
  __syncthreads();

  for (int it = tid; it < TT_FX * 8; it += 256) {
    int rt = it >> 3, o4 = it & 7;
    int t = t0 + rt;
    if (t >= T_) continue;
    if (e ? (t < 1017) : (t >= 7)) continue;
    float s2 = bn2w[o4] * rsqrtf(bn2v[o4] + 1e-5f);
    float t2 = bc2[o4] * s2 + bn2b[o4] - bn2m[o4] * s2;
    float acc = 0.f;
#pragma unroll
    for (int d = 0; d < 3; ++d) {
      const float* hr = (const float*)(smem + FXH1 + (rt + d) * 68);
#pragma unroll
      for (int ci = 0; ci < 16; ++ci)
        acc = fmaf(hr[ci], Wc2[(o4 * 16 + ci) * 3 + d], acc);
    }
    float v = acc * s2 + t2;
    out[((long)n * T_ + t) * 8 + o4] = v > 0.f ? v : 0.01f * v;
  }
}

extern "C" void kernel_launch(void* const* d_in, const int* in_sizes, int n_in,
                              void* d_out, int out_size, void* d_ws, size_t ws_size,
                              hipStream_t stream) {
  (void)in_sizes; (void)n_in; (void)out_size; (void)ws_size;
  const float* poses = (const float*)d_in[0];
  const float* A1    = (const float*)d_in[1];
  const float* A2    = (const float*)d_in[2];
  const float* W1    = (const float*)d_in[3];
  const float* b1    = (const float*)d_in[4];
  const float* W2    = (const float*)d_in[5];
  const float* b2    = (const float*)d_in[6];
  const float* Wc1   = (const float*)d_in[7];
  const float* bc1   = (const float*)d_in[8];
  const float* bn1w  = (const float*)d_in[9];
  const float* bn1b  = (const float*)d_in[10];
  const float* bn1m  = (const float*)d_in[11];
  const float* bn1v  = (const float*)d_in[12];
  const float* Wc2   = (const float*)d_in[13];
  const float* bc2   = (const float*)d_in[14];
  const float* bn2w  = (const float*)d_in[15];
  const float* bn2b  = (const float*)d_in[16];
  const float* bn2m  = (const float*)d_in[17];
  const float* bn2v  = (const float*)d_in[18];
  float* out = (float*)d_out;
  unsigned char* ws = (unsigned char*)d_ws;

  hipLaunchKernelGGL(prep_kernel, dim3(NPREP + 16), dim3(256), 0, stream,
                     A1, A2, W1, b1, W2, b2, Wc1, bc1, bn1w, bn1b, bn1m, bn1v,
                     Wc2, bc2, bn2w, bn2b, bn2m, bn2v, ws);
  hipLaunchKernelGGL(fused_kernel, dim3(6, NBATCH), dim3(256), 0, stream,
                     poses, Wc2, bc2, bn2w, bn2b, bn2m, bn2v, ws, out);
}

// Round 10
// 78.756 us; speedup vs baseline: 2.1325x; 2.1325x over previous
//
#include <hip/hip_runtime.h>

namespace {
constexpr int T_ = 1024;
constexpr int NBATCH = 256;

// ---- d_ws layout (bytes) ----
constexpr int WFB_OFF    = 0;         // 144 x 288 bf16 (stage1+A1, dh1-major K)
constexpr int WFC_OFF    = 82944;     // 48 x 1440 bf16 (stage2+A2, dh-major K)
constexpr int WFD_OFF    = 221184;    // 16 x 320 bf16 (conv1d5*bn1, d-major K)
constexpr int WBIG_OFF   = 231424;    // 16 x 672 bf16 (FULL composite, dt-major)
constexpr int WFE_OFF    = 252928;    // 16 x 64 bf16 (conv1d3*bn2, d-major)
constexpr int BIASB_OFF  = 254976;    // 144 f32
constexpr int BIASC_OFF  = 255552;    // 48 f32
constexpr int BIASD_OFF  = 255744;    // 16 f32
constexpr int BIASBIG_OFF= 255808;    // 16 f32
constexpr int BIASE_OFF  = 255872;    // 8 f32
constexpr int WCOMP_OFF  = 262144;    // 16*13*144 f32 = 119808 (ws scratch)

// prep1 item ranges
constexpr int R0 = 41472;             // wfB
constexpr int R1 = R0 + 69120;        // wfC
constexpr int R2 = R1 + 5120;         // wfD
constexpr int R3 = R2 + 1024;         // wfE
constexpr int R4 = R3 + 29952;        // wComp32
constexpr int R5 = R4 + 144;          // biasB
constexpr int R6 = R5 + 48;           // biasC
constexpr int R7 = R6 + 16;           // biasD
constexpr int R8 = R7 + 8;            // biasE

// ---- fused kernel LDS (bytes): max(main 27392, fixup 38592) ----
constexpr int SLAB_OFF  = 0;                     // main: 292 rows x 64 B
constexpr int H1_OFF    = 18688;                 // main: 272 rows x 32 B -> 27392
constexpr int TT_FX     = 50;
constexpr int FXF2IN    = 0;                     // 72 rows x 320
constexpr int FXF3      = FXF2IN + 72 * 320;     // 23040: 68 rows x 144
constexpr int FXSLAB    = FXF3 + 68 * 144;       // 32832: 72 rows x 80
constexpr int FXH1      = FXSLAB;                // overlay: 52 rows x 68B
constexpr int SMEM_FUSE = FXSLAB + 72 * 80;      // 38592
static_assert(SMEM_FUSE <= 65536, "fused LDS");

typedef __attribute__((ext_vector_type(8))) short short8v;
typedef __attribute__((ext_vector_type(4))) float f32x4;

__device__ inline unsigned short f2b(float f) {
  union { float f; unsigned u; } v; v.f = f;
  unsigned r = (v.u + 0x7FFFu + ((v.u >> 16) & 1u)) >> 16;
  return (unsigned short)r;
}
__device__ inline float b2f(unsigned short u) {
  union { unsigned u; float f; } v; v.u = ((unsigned)u) << 16;
  return v.f;
}
__device__ inline int fx_f2in_byte(int row, int slot, int within) {
  return FXF2IN + row * 320 + ((slot ^ ((row >> 2) & 3)) << 4) + within;
}
}

// ============ prep1: bf16 tables + wComp32 + wfE + biases ===================
__global__ __launch_bounds__(256) void prep1_kernel(
    const float* __restrict__ A1, const float* __restrict__ A2,
    const float* __restrict__ W1, const float* __restrict__ b1,
    const float* __restrict__ W2, const float* __restrict__ b2,
    const float* __restrict__ Wc1, const float* __restrict__ bc1,
    const float* __restrict__ bn1w, const float* __restrict__ bn1b,
    const float* __restrict__ bn1m, const float* __restrict__ bn1v,
    const float* __restrict__ Wc2, const float* __restrict__ bc2,
    const float* __restrict__ bn2w, const float* __restrict__ bn2b,
    const float* __restrict__ bn2m, const float* __restrict__ bn2v,
    unsigned char* __restrict__ ws) {
  unsigned short* wfB = (unsigned short*)(ws + WFB_OFF);
  unsigned short* wfC = (unsigned short*)(ws + WFC_OFF);
  unsigned short* wfD = (unsigned short*)(ws + WFD_OFF);
  unsigned short* wfE = (unsigned short*)(ws + WFE_OFF);
  float* biasB = (float*)(ws + BIASB_OFF);
  float* biasC = (float*)(ws + BIASC_OFF);
  float* biasD = (float*)(ws + BIASD_OFF);
  float* biasE = (float*)(ws + BIASE_OFF);
  float* wcomp = (float*)(ws + WCOMP_OFF);
  for (int idx = blockIdx.x * 256 + threadIdx.x; idx < R8; idx += gridDim.x * 256) {
    if (idx < R0) {                      // wfB[ncol][dh1*32+m1]
      int ncol = idx / 288, k = idx - ncol * 288;
      int dh = k >> 5, mm = k & 31;
      float val = 0.f;
      if (mm < 27) {
        int v = mm / 3, ci = mm - v * 3;
        int p = ncol / 48, rr = ncol - p * 48, c = rr / 3, e = rr - c * 3;
        int w = p * 3 + e;
        for (int k5 = 0; k5 < 5; ++k5)
          val += W1[(k5 * 16 + c) * 27 + ci * 9 + dh] * A1[k5 * 81 + v * 9 + w];
      }
      wfB[idx] = f2b(val);
    } else if (idx < R1) {               // wfC[nc][dh*160+off]
      int i2 = idx - R0;
      int nc = i2 / 1440, k = i2 - nc * 1440;
      int dh = k / 160, off = k - dh * 160;
      float val = 0.f;
      if (off < 144) {
        int p = off / 48, ci2 = off - p * 48;
        int c2 = nc / 3, w2 = nc - c2 * 3;
        for (int k2 = 0; k2 < 3; ++k2)
          val += W2[(k2 * 16 + c2) * 432 + ci2 * 9 + dh] * A2[k2 * 9 + p * 3 + w2];
      }
      wfC[i2] = f2b(val);
    } else if (idx < R2) {               // wfD[o3][d*64+nc]
      int i3 = idx - R1;
      int o3 = i3 / 320, k = i3 - o3 * 320;
      int d = k >> 6, nc = k & 63;
      float val = 0.f;
      if (nc < 48) {
        float s1 = bn1w[o3] * rsqrtf(bn1v[o3] + 1e-5f);
        val = Wc1[o3 * 240 + nc * 5 + d] * s1;
      }
      wfD[i3] = f2b(val);
    } else if (idx < R3) {               // wfE[o4p][d*16+ci]*s2
      int i4 = idx - R2;
      int o4 = i4 >> 6, k = i4 & 63;
      float val = 0.f;
      if (o4 < 8 && k < 48) {
        int d = k >> 4, ci = k & 15;
        float s2 = bn2w[o4] * rsqrtf(bn2v[o4] + 1e-5f);
        val = Wc2[(o4 * 16 + ci) * 3 + d] * s2;
      }
      wfE[i4] = f2b(val);
    } else if (idx < R4) {               // wComp32[o3][dh2][ncol] (f32, ws scratch)
      int i5 = idx - R3;
      int o3 = i5 / 1872, rem = i5 - o3 * 1872;
      int dh2 = rem / 144, ncol = rem - dh2 * 144;
      int p = ncol / 48, ci2 = ncol - p * 48;
      float s1 = bn1w[o3] * rsqrtf(bn1v[o3] + 1e-5f);
      float acc = 0.f;
      for (int d = 0; d < 5; ++d) {
        int dh = dh2 - d;
        if (dh < 0 || dh > 8) continue;
        float wd = 0.f;
        for (int nc = 0; nc < 48; ++nc) {
          int c2 = nc / 3, w2 = nc - c2 * 3;
          float wc = 0.f;
          for (int k2 = 0; k2 < 3; ++k2)
            wc += W2[(k2 * 16 + c2) * 432 + ci2 * 9 + dh] * A2[k2 * 9 + p * 3 + w2];
          wd += Wc1[o3 * 240 + nc * 5 + d] * wc;
        }
        acc += wd * s1;
      }
      wcomp[i5] = acc;
    } else if (idx < R5) {               // biasB
      int ib = idx - R4;
      int p = ib / 48, rr = ib - p * 48, c = rr / 3, e = rr - c * 3;
      int w = p * 3 + e;
      float val = 0.f;
      for (int k5 = 0; k5 < 5; ++k5)
        for (int v = 0; v < 9; ++v)
          val += b1[k5 * 16 + c] * A1[k5 * 81 + v * 9 + w];
      biasB[ib] = val;
    } else if (idx < R6) {               // biasC
      int nc = idx - R5, c2 = nc / 3, w2 = nc - c2 * 3;
      float val = 0.f;
      for (int k2 = 0; k2 < 3; ++k2)
        for (int p = 0; p < 3; ++p)
          val += b2[k2 * 16 + c2] * A2[k2 * 9 + p * 3 + w2];
      biasC[nc] = val;
    } else if (idx < R7) {               // biasD
      int o3 = idx - R6;
      float s1 = bn1w[o3] * rsqrtf(bn1v[o3] + 1e-5f);
      biasD[o3] = bc1[o3] * s1 + bn1b[o3] - bn1m[o3] * s1;
    } else {                             // biasE
      int o4 = idx - R7;
      float s2 = bn2w[o4] * rsqrtf(bn2v[o4] + 1e-5f);
      biasE[o4] = bc2[o4] * s2 + bn2b[o4] - bn2m[o4] * s2;
    }
  }
}

// ============ prep2: wBIG = wComp32 (x) wfB, biasBIG (parallel LDS) =========
// grid (21 dt, 16 o3), 256 threads = (m1:32) x (p:8); p owns 6 ncols/chunk.
__global__ __launch_bounds__(256) void prep2_kernel(
    const float* __restrict__ Wc1, const float* __restrict__ bn1w,
    const float* __restrict__ bn1v, unsigned char* __restrict__ ws) {
  __shared__ float stgf[48 * 288];   // wfB chunk, f32
  __shared__ float wl[1872];         // wComp[o3]
  __shared__ float pr[256];
  __shared__ float pbias[192];
  const int dt = blockIdx.x, o3 = blockIdx.y;
  const int tid = threadIdx.x;
  const int m1 = tid & 31, p = tid >> 5;
  const unsigned short* wfB = (const unsigned short*)(ws + WFB_OFF);
  const float* wcomp = (const float*)(ws + WCOMP_OFF);
  unsigned short* wBIG = (unsigned short*)(ws + WBIG_OFF);

  for (int i = tid; i < 1872; i += 256) wl[i] = wcomp[o3 * 1872 + i];

  const int lo = (dt - 8) > 0 ? (dt - 8) : 0;
  const int hi = (dt < 12) ? dt : 12;
  float acc = 0.f;
  for (int c = 0; c < 3; ++c) {
    __syncthreads();                       // stgf reads done (and wl ready at c=0)
    for (int i = tid; i < 48 * 288; i += 256)
      stgf[i] = b2f(wfB[c * 13824 + i]);   // contiguous coalesced u16 loads
    __syncthreads();
    for (int dh2 = lo; dh2 <= hi; ++dh2) {
      const int dh1 = dt - dh2;
      const float* wr = wl + dh2 * 144 + c * 48 + p * 6;
      const float* br = stgf + (p * 6) * 288 + dh1 * 32 + m1;
#pragma unroll
      for (int j = 0; j < 6; ++j)
        acc += wr[j] * br[j * 288];
    }
  }
  pr[tid] = acc;
  __syncthreads();
  if (tid < 32) {
    float s = pr[tid];
#pragma unroll
    for (int pp = 1; pp < 8; ++pp) s += pr[pp * 32 + tid];
    wBIG[o3 * 672 + dt * 32 + tid] = f2b(s);
  }
  if (dt == 0) {                           // block-uniform branch
    if (tid < 144) {
      float s = 0.f;
      for (int dh2 = 0; dh2 < 13; ++dh2) s += wl[dh2 * 144 + tid];
      pbias[tid] = s * ((const float*)(ws + BIASB_OFF))[tid];
    } else if (tid < 192) {
      int nc = tid - 144;
      float s1 = bn1w[o3] * rsqrtf(bn1v[o3] + 1e-5f);
      float s = 0.f;
#pragma unroll
      for (int d = 0; d < 5; ++d) s += Wc1[o3 * 240 + nc * 5 + d];
      pbias[tid] = s * s1 * ((const float*)(ws + BIASC_OFF))[nc];
    }
    __syncthreads();
    if (tid == 0) {
      float accb = ((const float*)(ws + BIASD_OFF))[o3];
      for (int i = 0; i < 192; ++i) accb += pbias[i];
      ((float*)(ws + BIASBIG_OFF))[o3] = accb;
    }
  }
}

// ============ fused: main composite (bx<4) + boundary fixup (bx 4,5) ========
__global__ __launch_bounds__(256, 3) void fused_kernel(
    const float* __restrict__ poses,
    const float* __restrict__ Wc2, const float* __restrict__ bc2,
    const float* __restrict__ bn2w, const float* __restrict__ bn2b,
    const float* __restrict__ bn2m, const float* __restrict__ bn2v,
    const unsigned char* __restrict__ ws, float* __restrict__ out) {
  __shared__ __attribute__((aligned(16))) unsigned char smem[SMEM_FUSE];
  const int tid = threadIdx.x;
  const int n = blockIdx.y;
  const int w = tid >> 6, l = tid & 63, lrow = l & 15, q = l >> 4, q8 = q * 8;

  if (blockIdx.x < 4) {
    // ================= MAIN path =================
    const int t0 = blockIdx.x * 256;
    {
      unsigned* s32 = (unsigned*)(smem + SLAB_OFF);
      for (int idx = tid; idx < 292 * 16; idx += 256) {
        int r = idx >> 4, mi = idx & 15, m0 = mi * 2;
        int t = t0 - 18 + r;
        float v0 = 0.f, v1 = 0.f;
        if (t >= 0 && t < T_) {
          const float* src = poses + ((long)n * T_ + t) * 27;
          if (m0 < 27) v0 = src[m0];
          if (m0 + 1 < 27) v1 = src[m0 + 1];
        }
        s32[idx] = (unsigned)f2b(v0) | ((unsigned)f2b(v1) << 16);
      }
    }

    const float bb = ((const float*)(ws + BIASBIG_OFF))[lrow];
    const float be = ((const float*)(ws + BIASE_OFF))[lrow & 7];
    const unsigned short* wbg = (const unsigned short*)(ws + WBIG_OFF);
    short8v B[21];
#pragma unroll
    for (int dt = 0; dt < 21; ++dt)
      B[dt] = *(const short8v*)(wbg + lrow * 672 + dt * 32 + q8);
    const unsigned short* wfe = (const unsigned short*)(ws + WFE_OFF);
    const short8v E0 = *(const short8v*)(wfe + lrow * 64 + q8);
    const short8v E1 = *(const short8v*)(wfe + lrow * 64 + 32 + q8);
    __syncthreads();

    // BIG GEMM: 272 h1 rows (t = t0-8+lr), 17 mt over waves
#pragma unroll
    for (int i = 0; i < 5; ++i) {
      if (i == 4 && w != 0) continue;
      const int mt = (i < 4) ? (w + i * 4) : 16;
      const int sbase = SLAB_OFF + (mt * 16 + lrow) * 64 + q8 * 2;
      f32x4 c0 = {0.f, 0.f, 0.f, 0.f}, c1 = {0.f, 0.f, 0.f, 0.f};
      short8v a[7];
#pragma unroll
      for (int dt = 0; dt < 7; ++dt) a[dt] = *(const short8v*)(smem + sbase + dt * 64);
#pragma unroll
      for (int dt = 0; dt < 7; ++dt) {
        if (dt & 1) c1 = __builtin_amdgcn_mfma_f32_16x16x32_bf16(a[dt], B[dt], c1, 0, 0, 0);
        else        c0 = __builtin_amdgcn_mfma_f32_16x16x32_bf16(a[dt], B[dt], c0, 0, 0, 0);
      }
#pragma unroll
      for (int dt = 0; dt < 7; ++dt) a[dt] = *(const short8v*)(smem + sbase + (7 + dt) * 64);
#pragma unroll
      for (int dt = 0; dt < 7; ++dt) {
        if (dt & 1) c1 = __builtin_amdgcn_mfma_f32_16x16x32_bf16(a[dt], B[7 + dt], c1, 0, 0, 0);
        else        c0 = __builtin_amdgcn_mfma_f32_16x16x32_bf16(a[dt], B[7 + dt], c0, 0, 0, 0);
      }
#pragma unroll
      for (int dt = 0; dt < 7; ++dt) a[dt] = *(const short8v*)(smem + sbase + (14 + dt) * 64);
#pragma unroll
      for (int dt = 0; dt < 7; ++dt) {
        if (dt & 1) c1 = __builtin_amdgcn_mfma_f32_16x16x32_bf16(a[dt], B[14 + dt], c1, 0, 0, 0);
        else        c0 = __builtin_amdgcn_mfma_f32_16x16x32_bf16(a[dt], B[14 + dt], c0, 0, 0, 0);
      }
      const int hbase = H1_OFF + (mt * 16 + q * 4) * 32 + lrow * 2;
#pragma unroll
      for (int jj = 0; jj < 4; ++jj) {
        float x = c0[jj] + c1[jj] + bb;
        float h = x > 0.f ? x : 0.01f * x;
        *(unsigned short*)(smem + hbase + jj * 32) = f2b(h);
      }
    }
    __syncthreads();

    // E GEMM; boundary rows left to fixup blocks
#pragma unroll
    for (int i = 0; i < 4; ++i) {
      const int mte = w + i * 4;
      const int abase = H1_OFF + (7 + mte * 16 + lrow) * 32 + q8 * 2;
      short8v A0v = *(const short8v*)(smem + abase);
      short8v A1v = *(const short8v*)(smem + abase + 64);
      f32x4 acc = {0.f, 0.f, 0.f, 0.f};
      acc = __builtin_amdgcn_mfma_f32_16x16x32_bf16(A0v, E0, acc, 0, 0, 0);
      acc = __builtin_amdgcn_mfma_f32_16x16x32_bf16(A1v, E1, acc, 0, 0, 0);
      if (lrow < 8) {
        const int tb = t0 + mte * 16 + q * 4;
#pragma unroll
        for (int jj = 0; jj < 4; ++jj) {
          const int t = tb + jj;
          if (t >= 7 && t < 1017) {
            float x = acc[jj] + be;
            out[((long)n * T_ + t) * 8 + lrow] = x > 0.f ? x : 0.01f * x;
          }
        }
      }
    }
    return;
  }

  // ================= FIXUP path (boundary rows only) =================
  const unsigned short* wfB = (const unsigned short*)(ws + WFB_OFF);
  const unsigned short* wfC = (const unsigned short*)(ws + WFC_OFF);
  const unsigned short* wfD = (const unsigned short*)(ws + WFD_OFF);
  const float* biasB = (const float*)(ws + BIASB_OFF);
  const float* biasC = (const float*)(ws + BIASC_OFF);
  const float* biasD = (const float*)(ws + BIASD_OFF);
  const int e = blockIdx.x - 4;
  const int t0 = e ? (T_ - TT_FX) : 0;

  {
    unsigned* slab32 = (unsigned*)(smem + FXSLAB);
    for (int it = tid; it < 72 * 20; it += 256) {
      int r = it / 20, mi = it - r * 20;
      int t = t0 - 11 + r;
      int m0 = mi * 2;
      float v0 = 0.f, v1 = 0.f;
      if (t >= 0 && t < T_) {
        const float* src = poses + ((long)n * T_ + t) * 27;
        if (m0 < 27) v0 = src[m0];
        if (m0 + 1 < 27) v1 = src[m0 + 1];
      }
      slab32[it] = (unsigned)f2b(v0) | ((unsigned)f2b(v1) << 16);
    }
    for (int it = tid; it < 64 * 8; it += 256) {
      int r = it >> 3, u = it & 7;
      int s = 18 + (u >> 2);
      *(unsigned*)(smem + fx_f2in_byte(r, s, (u & 3) * 4)) = 0;
    }
    for (int it = tid; it < 8 * 80; it += 256) {
      int r = 64 + it / 80, u = it - (it / 80) * 80;
      *(unsigned*)(smem + FXF2IN + r * 320 + u * 4) = 0;
    }
    for (int it = tid; it < 68 * 8 + 12 * 24; it += 256) {
      if (it < 68 * 8) {
        int r = it >> 3, u = it & 7;
        *(unsigned*)(smem + FXF3 + r * 144 + 96 + u * 4) = 0;
      } else {
        int k2 = it - 68 * 8;
        int r = 56 + k2 / 24, u = k2 - (k2 / 24) * 24;
        *(unsigned*)(smem + FXF3 + r * 144 + u * 4) = 0;
      }
    }
  }
  __syncthreads();

  {  // GEMM B
    const int ntS = (w == 0) ? 0 : (2 * w + 1);
    const int ntN = (w == 0) ? 3 : 2;
#pragma unroll
    for (int ni = 0; ni < 3; ++ni) {
      if (ni < ntN) {
        const int nt = ntS + ni;
        short8v b[9];
#pragma unroll
        for (int dh = 0; dh < 9; ++dh)
          b[dh] = *(const short8v*)(wfB + (nt * 16 + lrow) * 288 + dh * 32 + q8);
        const int ncol = nt * 16 + lrow;
        const float bias = biasB[ncol];
#pragma unroll
        for (int mt = 0; mt < 4; ++mt) {
          short8v a[9];
#pragma unroll
          for (int dh = 0; dh < 9; ++dh)
            a[dh] = *(const short8v*)(smem + FXSLAB + ((mt * 16 + lrow + dh) * 40 + q8) * 2);
          f32x4 c0 = {0.f, 0.f, 0.f, 0.f}, c1 = {0.f, 0.f, 0.f, 0.f};
#pragma unroll
          for (int dh = 0; dh < 9; ++dh) {
            if (dh & 1) c1 = __builtin_amdgcn_mfma_f32_16x16x32_bf16(a[dh], b[dh], c1, 0, 0, 0);
            else        c0 = __builtin_amdgcn_mfma_f32_16x16x32_bf16(a[dh], b[dh], c0, 0, 0, 0);
          }
#pragma unroll
          for (int jj = 0; jj < 4; ++jj) {
            const int r = mt * 16 + q * 4 + jj;
            const int t = t0 - 7 + r;
            float v = (t >= 0 && t < T_) ? c0[jj] + c1[jj] + bias : 0.f;
            *(unsigned short*)(smem + fx_f2in_byte(r, ncol >> 3, (ncol & 7) * 2)) = f2b(v);
          }
        }
      }
    }
  }
  __syncthreads();

  if (w < 3) {  // GEMM C
    const int ncol2 = w * 16 + lrow;
    const float bias = biasC[ncol2];
    f32x4 acc[4];
#pragma unroll
    for (int mt = 0; mt < 4; ++mt) acc[mt] = {0.f, 0.f, 0.f, 0.f};
#pragma unroll
    for (int g = 0; g < 5; ++g) {
      short8v b[9];
#pragma unroll
      for (int i = 0; i < 9; ++i) {
        const int kf = g * 9 + i, dh = kf / 5, kkl = kf % 5;
        b[i] = *(const short8v*)(wfC + ncol2 * 1440 + dh * 160 + kkl * 32 + q8);
      }
#pragma unroll
      for (int mt = 0; mt < 4; ++mt) {
        short8v a[9];
#pragma unroll
        for (int i = 0; i < 9; ++i) {
          const int kf = g * 9 + i, dh = kf / 5, kkl = kf % 5;
          a[i] = *(const short8v*)(smem + fx_f2in_byte(mt * 16 + lrow + dh, 4 * kkl + q, 0));
        }
#pragma unroll
        for (int i = 0; i < 9; ++i)
          acc[mt] = __builtin_amdgcn_mfma_f32_16x16x32_bf16(a[i], b[i], acc[mt], 0, 0, 0);
      }
    }
#pragma unroll
    for (int mt = 0; mt < 4; ++mt) {
#pragma unroll
      for (int jj = 0; jj < 4; ++jj) {
        const int rt3 = mt * 16 + q * 4 + jj;
        if (rt3 < 56) {
          const int t = t0 - 3 + rt3;
          float v = (t >= 0 && t < T_) ? acc[mt][jj] + bias : 0.f;
          *(unsigned short*)(smem + FXF3 + rt3 * 144 + ncol2 * 2) = f2b(v);
        }
      }
    }
  }
  __syncthreads();

  {  // GEMM D
    const int arow = w * 16 + lrow;
    short8v a[10], b[10];
#pragma unroll
    for (int kf = 0; kf < 10; ++kf) {
      const int d = kf >> 1, kkl = kf & 1;
      b[kf] = *(const short8v*)(wfD + lrow * 320 + d * 64 + kkl * 32 + q8);
      a[kf] = *(const short8v*)(smem + FXF3 + (arow + d) * 144 + (kkl * 32 + q8) * 2);
    }
    f32x4 c0 = {0.f, 0.f, 0.f, 0.f}, c1 = {0.f, 0.f, 0.f, 0.f};
#pragma unroll
    for (int kf = 0; kf < 10; ++kf) {
      if (kf & 1) c1 = __builtin_amdgcn_mfma_f32_16x16x32_bf16(a[kf], b[kf], c1, 0, 0, 0);
      else        c0 = __builtin_amdgcn_mfma_f32_16x16x32_bf16(a[kf], b[kf], c0, 0, 0, 0);
    }
    const float bias = biasD[lrow];
#pragma unroll
    for (int jj = 0; jj < 4; ++jj) {
      const int rh = w * 16 + q * 4 + jj;
      if (rh < 52) {
        const int t = t0 - 1 + rh;
        float v = 0.f;
        if (t >= 0 && t < T_) {
          float x = c0[jj] + c1[jj] + bias;
          v = x > 0.f ? x : 0.01f * x;
        }
        *(float*)(smem + FXH1 + (rh * 17 + lrow) * 4) = v;
      }
    }
  }
  __syncthreads();

  for (int it = tid; it < TT_FX * 8; it += 256) {
    int rt = it >> 3, o4 = it & 7;
    int t = t0 + rt;
    if (t >= T_) continue;
    if (e ? (t < 1017) : (t >= 7)) continue;
    float s2 = bn2w[o4] * rsqrtf(bn2v[o4] + 1e-5f);
    float t2 = bc2[o4] * s2 + bn2b[o4] - bn2m[o4] * s2;
    float acc = 0.f;
#pragma unroll
    for (int d = 0; d < 3; ++d) {
      const float* hr = (const float*)(smem + FXH1 + (rt + d) * 68);
#pragma unroll
      for (int ci = 0; ci < 16; ++ci)
        acc = fmaf(hr[ci], Wc2[(o4 * 16 + ci) * 3 + d], acc);
    }
    float v = acc * s2 + t2;
    out[((long)n * T_ + t) * 8 + o4] = v > 0.f ? v : 0.01f * v;
  }
}

extern "C" void kernel_launch(void* const* d_in, const int* in_sizes, int n_in,
                              void* d_out, int out_size, void* d_ws, size_t ws_size,
                              hipStream_t stream) {
  (void)in_sizes; (void)n_in; (void)out_size; (void)ws_size;
  const float* poses = (const float*)d_in[0];
  const float* A1    = (const float*)d_in[1];
  const float* A2    = (const float*)d_in[2];
  const float* W1    = (const float*)d_in[3];
  const float* b1    = (const float*)d_in[4];
  const float* W2    = (const float*)d_in[5];
  const float* b2    = (const float*)d_in[6];
  const float* Wc1   = (const float*)d_in[7];
  const float* bc1   = (const float*)d_in[8];
  const float* bn1w  = (const float*)d_in[9];
  const float* bn1b  = (const float*)d_in[10];
  const float* bn1m  = (const float*)d_in[11];
  const float* bn1v  = (const float*)d_in[12];
  const float* Wc2   = (const float*)d_in[13];
  const float* bc2   = (const float*)d_in[14];
  const float* bn2w  = (const float*)d_in[15];
  const float* bn2b  = (const float*)d_in[16];
  const float* bn2m  = (const float*)d_in[17];
  const float* bn2v  = (const float*)d_in[18];
  float* out = (float*)d_out;
  unsigned char* ws = (unsigned char*)d_ws;

  hipLaunchKernelGGL(prep1_kernel, dim3(144), dim3(256), 0, stream,
                     A1, A2, W1, b1, W2, b2, Wc1, bc1, bn1w, bn1b, bn1m, bn1v,
                     Wc2, bc2, bn2w, bn2b, bn2m, bn2v, ws);
  hipLaunchKernelGGL(prep2_kernel, dim3(21, 16), dim3(256), 0, stream,
                     Wc1, bn1w, bn1v, ws);
  hipLaunchKernelGGL(fused_kernel, dim3(6, NBATCH), dim3(256), 0, stream,
                     poses, Wc2, bc2, bn2w, bn2b, bn2m, bn2v, ws, out);
}